// Round 6
// baseline (263.445 us; speedup 1.0000x reference)
//
#include <hip/hip_runtime.h>

#define D 128
#define NG 64
#define NC 16
#define NEG 0.1f

typedef __attribute__((ext_vector_type(8))) short bf16x8;
typedef __attribute__((ext_vector_type(4))) float f32x4;

// ---------- bf16 <-> fp32 helpers (bf16 stored as ushort, packed pairs in uint) ----------
__device__ __forceinline__ float bf2f(unsigned int u16) {
    union { unsigned int i; float f; } c;
    c.i = u16 << 16;
    return c.f;
}
__device__ __forceinline__ unsigned short f2bf(float f) {
    union { float f; unsigned int i; } c;
    c.f = f;
    unsigned int i = c.i;
    unsigned int r = (i + 0x7FFFu + ((i >> 16) & 1u)) >> 16;  // RNE
    return (unsigned short)r;
}

// ---------------- fused prep ----------------
// blocks 0..15: W1/W2 -> bf16 fragment-order image; 16..47: zero pooled; 48+: degree histogram.
// Fragment order: entry (((t*4+kc)*4+quad)*16+m) = 8 bf16 of W[k][n], k=kc*32+quad*8.., n=t*16+m.
__global__ void prep_misc_kernel(const float* __restrict__ W1, unsigned short* __restrict__ Wf1,
                                 const float* __restrict__ W2, unsigned short* __restrict__ Wf2,
                                 float* __restrict__ pooled,
                                 const int* __restrict__ dst, int* __restrict__ deg, int E) {
    int b = blockIdx.x;
    if (b < 16) {
        const float* W = (b < 8) ? W1 : W2;
        unsigned short* Wf = (b < 8) ? Wf1 : Wf2;
        int fid = (b & 7) * 256 + threadIdx.x;  // 0..2047 fragment entries
        int m = fid & 15;
        int quad = (fid >> 4) & 3;
        int kc = (fid >> 6) & 3;
        int t = fid >> 8;
        int n = t * 16 + m;
        int k0 = kc * 32 + quad * 8;
        unsigned short r[8];
#pragma unroll
        for (int j = 0; j < 8; j++) r[j] = f2bf(W[(k0 + j) * 128 + n]);
        uint4 v;
        v.x = (unsigned int)r[0] | ((unsigned int)r[1] << 16);
        v.y = (unsigned int)r[2] | ((unsigned int)r[3] << 16);
        v.z = (unsigned int)r[4] | ((unsigned int)r[5] << 16);
        v.w = (unsigned int)r[6] | ((unsigned int)r[7] << 16);
        ((uint4*)Wf)[fid] = v;
    } else if (b < 48) {
        pooled[(b - 16) * 256 + threadIdx.x] = 0.f;
    } else {
        int e = (b - 48) * 256 + threadIdx.x;
        if (e < E) atomicAdd(&deg[dst[e]], 1);
    }
}

// ---------------- scan stage 1 (+ dinv fold) ----------------
__global__ void scan_block_kernel(const int* __restrict__ deg, int* __restrict__ scan1,
                                  int* __restrict__ blocksum, float* __restrict__ dinv, int N) {
    __shared__ int sm[256];
    int tid = threadIdx.x;
    int i = blockIdx.x * 256 + tid;
    int v = (i < N) ? deg[i] : 0;
    if (i < N) dinv[i] = 1.0f / sqrtf((float)v + 1.0f);
    sm[tid] = v;
    __syncthreads();
    for (int off = 1; off < 256; off <<= 1) {
        int t = (tid >= off) ? sm[tid - off] : 0;
        __syncthreads();
        sm[tid] += t;
        __syncthreads();
    }
    if (i < N) scan1[i] = sm[tid];  // inclusive
    if (tid == 255) blocksum[blockIdx.x] = sm[255];
}

// ---------------- finalize: ptr = exclusive prefix; each block re-scans blocksum in LDS ----------
// (nscan <= 256 guaranteed: N <= 65536). Also zeroes fill[] ahead of scatter.
__global__ void finalize_ptr_kernel(const int* __restrict__ deg, const int* __restrict__ scan1,
                                    const int* __restrict__ blocksum, int* __restrict__ ptr,
                                    int* __restrict__ fill, int nb, int N, int E) {
    __shared__ int sm[256];
    int tid = threadIdx.x;
    int v = (tid < nb) ? blocksum[tid] : 0;
    sm[tid] = v;
    __syncthreads();
    for (int off = 1; off < 256; off <<= 1) {
        int t = (tid >= off) ? sm[tid - off] : 0;
        __syncthreads();
        sm[tid] += t;
        __syncthreads();
    }
    int blockoff = (blockIdx.x > 0) ? sm[blockIdx.x - 1] : 0;  // exclusive prefix for this block
    int i = blockIdx.x * 256 + tid;
    if (i < N) {
        ptr[i] = scan1[i] - deg[i] + blockoff;
        fill[i] = 0;
        if (i == N - 1) ptr[N] = E;
    }
}

// ---------------- scatter edges into CSR by dst; packed (src, coef) int2 ----------------
// coef precomputed HERE (R2/R3 lesson: per-edge dinv loads inside combine's gather loop hurt).
__global__ void scatter_kernel(const int* __restrict__ src, const int* __restrict__ dst,
                               const int* __restrict__ ptr, int* __restrict__ fill,
                               const float* __restrict__ dinv,
                               int2* __restrict__ csr_edge, int E) {
    int e = blockIdx.x * blockDim.x + threadIdx.x;
    if (e < E) {
        int d = dst[e];
        int s = src[e];
        int pos = ptr[d] + atomicAdd(&fill[d], 1);
        float coef = dinv[s] * dinv[d];
        csr_edge[pos] = make_int2(s, __float_as_int(coef));
    }
}

// ---------------- MFMA GEMM: C[N,128](packed bf16) = A[N,128] @ W ----------------
// 256 thr (4 waves), 64 rows/block. A fragments straight from global (read once);
// W (fragment-order bf16 image, 32 KB) staged to LDS 1:1, read as contiguous 1KB/wave.
template <bool AF32>
__global__ __launch_bounds__(256) void gemm_mfma_kernel(const void* __restrict__ Ap,
                                                        const uint4* __restrict__ Wf,
                                                        unsigned int* __restrict__ C, int N) {
    __shared__ uint4 Ws[2048];  // 32 KB, fragment-order image
    int tid = threadIdx.x;
    int w = tid >> 6, lane = tid & 63;
    int quad = lane >> 4, m = lane & 15;
    int rowstart = blockIdx.x * 64;

    // stage W image (contiguous copy)
#pragma unroll
    for (int i = 0; i < 8; i++) Ws[tid + 256 * i] = Wf[tid + 256 * i];

    // A fragments from global: row 16w+m, k = kc*32 + quad*8 + j
    int arow = rowstart + 16 * w + m;
    bool valid = arow < N;
    bf16x8 af[4];
    if (AF32) {
        const float* Ag = (const float*)Ap;
#pragma unroll
        for (int kc = 0; kc < 4; kc++) {
            float4 f0 = make_float4(0.f, 0.f, 0.f, 0.f), f1 = f0;
            if (valid) {
                const float4* p = (const float4*)(Ag + (size_t)arow * 128 + kc * 32 + quad * 8);
                f0 = p[0];
                f1 = p[1];
            }
            bf16x8 a;
            a[0] = (short)f2bf(f0.x); a[1] = (short)f2bf(f0.y);
            a[2] = (short)f2bf(f0.z); a[3] = (short)f2bf(f0.w);
            a[4] = (short)f2bf(f1.x); a[5] = (short)f2bf(f1.y);
            a[6] = (short)f2bf(f1.z); a[7] = (short)f2bf(f1.w);
            af[kc] = a;
        }
    } else {
        const unsigned short* Ag = (const unsigned short*)Ap;
#pragma unroll
        for (int kc = 0; kc < 4; kc++) {
            bf16x8 a;
#pragma unroll
            for (int j = 0; j < 8; j++) a[j] = 0;
            if (valid) a = *(const bf16x8*)(Ag + (size_t)arow * 128 + kc * 32 + quad * 8);
            af[kc] = a;
        }
    }
    __syncthreads();

    f32x4 acc[8];
#pragma unroll
    for (int t = 0; t < 8; t++) acc[t] = (f32x4){0.f, 0.f, 0.f, 0.f};

#pragma unroll
    for (int t = 0; t < 8; t++) {
#pragma unroll
        for (int kc = 0; kc < 4; kc++) {
            bf16x8 bh = *(const bf16x8*)&Ws[(((t * 4 + kc) * 4 + quad) * 16 + m)];
            acc[t] = __builtin_amdgcn_mfma_f32_16x16x32_bf16(af[kc], bh, acc[t], 0, 0, 0);
        }
    }

    // epilogue: C[row = 16w + quad*4 + r][col = t*16 + m]; pack pairs across m via shfl_xor(1)
    // (shfl in CONVERGENT code: all 64 lanes active -> defined)
#pragma unroll
    for (int t = 0; t < 8; t++) {
#pragma unroll
        for (int r = 0; r < 4; r++) {
            int row = rowstart + 16 * w + quad * 4 + r;
            unsigned int us = f2bf(acc[t][r]);
            unsigned int other = (unsigned int)__shfl_xor((int)us, 1);
            if (((m & 1) == 0) && row < N)
                C[(size_t)row * 64 + t * 8 + (m >> 1)] = us | (other << 16);
        }
    }
}

// ---------------- gather + self-loop + bias + leaky_relu ----------------
// R6 structure: 8 consecutive nodes per wave, one node per 8-lane OCTANT (lane l8 covers
// feats [l8*8,l8*8+8) and [64+l8*8,...), i.e. 2 uint4 per edge). Wave's CSR slice
// [ptr[nb],ptr[nb+8]) contiguous, staged to a wave-private LDS strip in 64-edge windows
// (broadcast ds_read; 8 distinct addrs/wave, 8 lanes each -> conflict-free).
// 4-deep unrolled gathers -> up to 64 outstanding loads/wave (2x R1's MLP), half the waves.
// Serial tail RESTORED (R5 lesson: clamped groups' wasted 256B gathers cost more than the
// short dependent tail).
#define ACC8A(v, c)                                                        \
    a0 += bf2f((v).x & 0xffffu) * (c); a1 += bf2f((v).x >> 16) * (c);      \
    a2 += bf2f((v).y & 0xffffu) * (c); a3 += bf2f((v).y >> 16) * (c);      \
    a4 += bf2f((v).z & 0xffffu) * (c); a5 += bf2f((v).z >> 16) * (c);      \
    a6 += bf2f((v).w & 0xffffu) * (c); a7 += bf2f((v).w >> 16) * (c);
#define ACC8B(v, c)                                                        \
    a8 += bf2f((v).x & 0xffffu) * (c); a9 += bf2f((v).x >> 16) * (c);      \
    aA += bf2f((v).y & 0xffffu) * (c); aB += bf2f((v).y >> 16) * (c);      \
    aC += bf2f((v).z & 0xffffu) * (c); aD += bf2f((v).z >> 16) * (c);      \
    aE += bf2f((v).w & 0xffffu) * (c); aF += bf2f((v).w >> 16) * (c);

__global__ __launch_bounds__(256) void combine_kernel(const uint4* __restrict__ h4,
                                                      const int* __restrict__ ptr,
                                                      const int2* __restrict__ csr_edge,
                                                      const float* __restrict__ dinv,
                                                      const float* __restrict__ b,
                                                      uint4* __restrict__ out4, int N) {
    __shared__ int2 smeta[4][64];  // 2 KB, one strip per wave
    int wave = threadIdx.x >> 6;
    int lane = threadIdx.x & 63;
    int oct = lane >> 3;   // 0..7: which of the wave's 8 nodes
    int l8 = lane & 7;     // lane within the node's row
    int nb = blockIdx.x * 32 + wave * 8;  // first node of this wave
    if (nb >= N) return;                  // wave-uniform exit; kernel uses no barriers
    int node = nb + oct;
    bool valid = node < N;

    int wlo = ptr[nb];
    int whi = ptr[min(nb + 8, N)];
    int lo = valid ? ptr[node] : 0;
    int hi = valid ? ptr[node + 1] : 0;

    // prefetch self row / dinv / bias — overlaps the gather loop
    float di = valid ? dinv[node] : 0.f;
    uint4 svA = valid ? h4[(size_t)node * 16 + l8] : make_uint4(0u, 0u, 0u, 0u);
    uint4 svB = valid ? h4[(size_t)node * 16 + 8 + l8] : make_uint4(0u, 0u, 0u, 0u);
    float4 bv0 = ((const float4*)b)[l8 * 2];
    float4 bv1 = ((const float4*)b)[l8 * 2 + 1];
    float4 bv2 = ((const float4*)b)[16 + l8 * 2];
    float4 bv3 = ((const float4*)b)[17 + l8 * 2];

    float a0 = 0.f, a1 = 0.f, a2 = 0.f, a3 = 0.f, a4 = 0.f, a5 = 0.f, a6 = 0.f, a7 = 0.f;
    float a8 = 0.f, a9 = 0.f, aA = 0.f, aB = 0.f, aC = 0.f, aD = 0.f, aE = 0.f, aF = 0.f;

#pragma unroll 1
    for (int base = wlo; base < whi; base += 64) {
        // cooperative, coalesced stage of the wave's next 64 edges (all 64 lanes)
        if (base + lane < whi) smeta[wave][lane] = csr_edge[base + lane];
        // wave-private strip: same-wave DS ordering (compiler lgkmcnt) suffices, no barrier.
        int s = max(lo, base);
        int e = min(hi, base + 64);
        int j = s;
#pragma unroll 1
        for (; j + 3 < e; j += 4) {
            int k = j - base;
            int2 e0 = smeta[wave][k];      // 8 lanes same addr -> LDS broadcast
            int2 e1 = smeta[wave][k + 1];
            int2 e2 = smeta[wave][k + 2];
            int2 e3 = smeta[wave][k + 3];
            uint4 v0a = h4[(size_t)e0.x * 16 + l8];
            uint4 v0b = h4[(size_t)e0.x * 16 + 8 + l8];
            uint4 v1a = h4[(size_t)e1.x * 16 + l8];
            uint4 v1b = h4[(size_t)e1.x * 16 + 8 + l8];
            uint4 v2a = h4[(size_t)e2.x * 16 + l8];
            uint4 v2b = h4[(size_t)e2.x * 16 + 8 + l8];
            uint4 v3a = h4[(size_t)e3.x * 16 + l8];
            uint4 v3b = h4[(size_t)e3.x * 16 + 8 + l8];
            float c0 = __int_as_float(e0.y);
            float c1 = __int_as_float(e1.y);
            float c2 = __int_as_float(e2.y);
            float c3 = __int_as_float(e3.y);
            ACC8A(v0a, c0) ACC8B(v0b, c0)
            ACC8A(v1a, c1) ACC8B(v1b, c1)
            ACC8A(v2a, c2) ACC8B(v2b, c2)
            ACC8A(v3a, c3) ACC8B(v3b, c3)
        }
#pragma unroll 1
        for (; j < e; j++) {
            int k = j - base;
            int2 e0 = smeta[wave][k];
            uint4 v0a = h4[(size_t)e0.x * 16 + l8];
            uint4 v0b = h4[(size_t)e0.x * 16 + 8 + l8];
            float c0 = __int_as_float(e0.y);
            ACC8A(v0a, c0) ACC8B(v0b, c0)
        }
    }

    if (!valid) return;
    float dd = di * di;
    float v0 = a0 + bf2f(svA.x & 0xffffu) * dd + bv0.x;
    float v1 = a1 + bf2f(svA.x >> 16) * dd + bv0.y;
    float v2 = a2 + bf2f(svA.y & 0xffffu) * dd + bv0.z;
    float v3 = a3 + bf2f(svA.y >> 16) * dd + bv0.w;
    float v4 = a4 + bf2f(svA.z & 0xffffu) * dd + bv1.x;
    float v5 = a5 + bf2f(svA.z >> 16) * dd + bv1.y;
    float v6 = a6 + bf2f(svA.w & 0xffffu) * dd + bv1.z;
    float v7 = a7 + bf2f(svA.w >> 16) * dd + bv1.w;
    float v8 = a8 + bf2f(svB.x & 0xffffu) * dd + bv2.x;
    float v9 = a9 + bf2f(svB.x >> 16) * dd + bv2.y;
    float vA = aA + bf2f(svB.y & 0xffffu) * dd + bv2.z;
    float vB = aB + bf2f(svB.y >> 16) * dd + bv2.w;
    float vC = aC + bf2f(svB.z & 0xffffu) * dd + bv3.x;
    float vD = aD + bf2f(svB.z >> 16) * dd + bv3.y;
    float vE = aE + bf2f(svB.w & 0xffffu) * dd + bv3.z;
    float vF = aF + bf2f(svB.w >> 16) * dd + bv3.w;
    v0 = (v0 >= 0.f) ? v0 : NEG * v0;
    v1 = (v1 >= 0.f) ? v1 : NEG * v1;
    v2 = (v2 >= 0.f) ? v2 : NEG * v2;
    v3 = (v3 >= 0.f) ? v3 : NEG * v3;
    v4 = (v4 >= 0.f) ? v4 : NEG * v4;
    v5 = (v5 >= 0.f) ? v5 : NEG * v5;
    v6 = (v6 >= 0.f) ? v6 : NEG * v6;
    v7 = (v7 >= 0.f) ? v7 : NEG * v7;
    v8 = (v8 >= 0.f) ? v8 : NEG * v8;
    v9 = (v9 >= 0.f) ? v9 : NEG * v9;
    vA = (vA >= 0.f) ? vA : NEG * vA;
    vB = (vB >= 0.f) ? vB : NEG * vB;
    vC = (vC >= 0.f) ? vC : NEG * vC;
    vD = (vD >= 0.f) ? vD : NEG * vD;
    vE = (vE >= 0.f) ? vE : NEG * vE;
    vF = (vF >= 0.f) ? vF : NEG * vF;
    uint4 pva, pvb;
    pva.x = (unsigned int)f2bf(v0) | ((unsigned int)f2bf(v1) << 16);
    pva.y = (unsigned int)f2bf(v2) | ((unsigned int)f2bf(v3) << 16);
    pva.z = (unsigned int)f2bf(v4) | ((unsigned int)f2bf(v5) << 16);
    pva.w = (unsigned int)f2bf(v6) | ((unsigned int)f2bf(v7) << 16);
    pvb.x = (unsigned int)f2bf(v8) | ((unsigned int)f2bf(v9) << 16);
    pvb.y = (unsigned int)f2bf(vA) | ((unsigned int)f2bf(vB) << 16);
    pvb.z = (unsigned int)f2bf(vC) | ((unsigned int)f2bf(vD) << 16);
    pvb.w = (unsigned int)f2bf(vE) | ((unsigned int)f2bf(vF) << 16);
    out4[(size_t)node * 16 + l8] = pva;
    out4[(size_t)node * 16 + 8 + l8] = pvb;
}

// ---------------- pool: node-parallel chunked accumulate (batch sorted) ----------------
// R2/R3 lesson: do NOT fuse pooling into combine — the fused version's 1.6M device-scope
// f32 atomics onto 8KB serialized at the coherence point and cost ~100us.
#define PROWS 128
__global__ void pool_accum_kernel(const unsigned int* __restrict__ a2,
                                  const int* __restrict__ batch,
                                  float* __restrict__ pooled, int N) {
    int wave = threadIdx.x >> 6;
    int lane = threadIdx.x & 63;
    int start = blockIdx.x * PROWS;
    int end = start + PROWS;
    if (end > N) end = N;
    float s0 = 0.f, s1 = 0.f;
    int curg = -1;
    for (int r = start + wave; r < end; r += 4) {
        int g = batch[r];  // wave-uniform (sorted batch)
        if (g != curg) {
            if (curg >= 0) {
                atomicAdd(&pooled[curg * D + 2 * lane], s0);
                atomicAdd(&pooled[curg * D + 2 * lane + 1], s1);
            }
            curg = g;
            s0 = 0.f;
            s1 = 0.f;
        }
        unsigned int v = a2[(size_t)r * 64 + lane];
        s0 += bf2f(v & 0xffffu);
        s1 += bf2f(v >> 16);
    }
    if (curg >= 0) {
        atomicAdd(&pooled[curg * D + 2 * lane], s0);
        atomicAdd(&pooled[curg * D + 2 * lane + 1], s1);
    }
}

// ---------------- final linear: out[g,c] = (sum[g]/cnt[g]) . Wl[:,c] + bl[c] ----------------
__global__ void final_kernel(const float* __restrict__ pooled, const int* __restrict__ batch,
                             const float* __restrict__ Wl, const float* __restrict__ bl,
                             float* __restrict__ out, int N) {
    int t = blockIdx.x * blockDim.x + threadIdx.x;
    if (t >= NG * NC) return;
    int g = t >> 4, c = t & 15;
    int l = 0, h = N;
    while (l < h) { int m = (l + h) >> 1; if (batch[m] < g) l = m + 1; else h = m; }
    int lo = l;
    h = N;
    while (l < h) { int m = (l + h) >> 1; if (batch[m] < g + 1) l = m + 1; else h = m; }
    int cnt = l - lo;
    float inv = 1.0f / (float)(cnt > 0 ? cnt : 1);
    float dot = 0.f;
    for (int k = 0; k < D; k++) dot += pooled[g * D + k] * Wl[k * NC + c];
    out[t] = dot * inv + bl[c];
}

extern "C" void kernel_launch(void* const* d_in, const int* in_sizes, int n_in,
                              void* d_out, int out_size, void* d_ws, size_t ws_size,
                              hipStream_t stream) {
    const float* x = (const float*)d_in[0];
    const int* ei = (const int*)d_in[1];
    const int* batch = (const int*)d_in[2];
    const float* W1 = (const float*)d_in[3];
    const float* b1 = (const float*)d_in[4];
    const float* W2 = (const float*)d_in[5];
    const float* b2 = (const float*)d_in[6];
    const float* Wlin = (const float*)d_in[7];
    const float* bl = (const float*)d_in[8];
    float* out = (float*)d_out;

    int N = in_sizes[0] / D;
    int E = in_sizes[1] / 2;
    const int* src = ei;
    const int* dst = ei + E;

    // workspace layout (float units). 128x128 bf16 array = 16384 shorts = 8192 floats.
    float* ws = (float*)d_ws;
    size_t o = 0;
    unsigned int* bufA = (unsigned int*)(ws + o); o += (size_t)N * 64;  // 12.8 MB
    unsigned int* bufB = (unsigned int*)(ws + o); o += (size_t)N * 64;  // 12.8 MB
    int* deg = (int*)(ws + o);      o += N;       // zeroed by memset below
    int* fill = (int*)(ws + o);     o += N;       // zeroed inside finalize_ptr
    float* dinv = ws + o;           o += N;
    int* scan1 = (int*)(ws + o);    o += N;
    int* blocksum = (int*)(ws + o); o += 256;
    int* csr_ptr = (int*)(ws + o);  o += (N + 8);
    int2* csr_edge = (int2*)(ws + o); o += (size_t)2 * E;
    float* pooled = ws + o;         o += NG * D;
    unsigned short* Wf1 = (unsigned short*)(ws + o); o += 8192;  // fragment-order bf16 image
    unsigned short* Wf2 = (unsigned short*)(ws + o); o += 8192;

    hipMemsetAsync(deg, 0, (size_t)N * sizeof(int), stream);

    int tb = 256;
    int nscan = (N + 255) / 256;
    prep_misc_kernel<<<48 + (E + 255) / 256, 256, 0, stream>>>(W1, Wf1, W2, Wf2, pooled,
                                                               dst, deg, E);
    scan_block_kernel<<<nscan, 256, 0, stream>>>(deg, scan1, blocksum, dinv, N);
    finalize_ptr_kernel<<<nscan, 256, 0, stream>>>(deg, scan1, blocksum, csr_ptr, fill,
                                                   nscan, N, E);
    scatter_kernel<<<(E + tb - 1) / tb, tb, 0, stream>>>(src, dst, csr_ptr, fill, dinv,
                                                         csr_edge, E);

    int gblocks = (N + 63) / 64;
    int cblocks = (N + 31) / 32;
    // layer 1
    gemm_mfma_kernel<true><<<gblocks, 256, 0, stream>>>(x, (const uint4*)Wf1,
                                                        (unsigned int*)bufA, N);
    combine_kernel<<<cblocks, 256, 0, stream>>>((const uint4*)bufA, csr_ptr, csr_edge,
                                                dinv, b1, (uint4*)bufB, N);
    // layer 2
    gemm_mfma_kernel<false><<<gblocks, 256, 0, stream>>>(bufB, (const uint4*)Wf2,
                                                         (unsigned int*)bufA, N);
    combine_kernel<<<cblocks, 256, 0, stream>>>((const uint4*)bufA, csr_ptr, csr_edge,
                                                dinv, b2, (uint4*)bufB, N);
    // pool + classifier
    pool_accum_kernel<<<(N + PROWS - 1) / PROWS, 256, 0, stream>>>(bufB, batch, pooled, N);
    final_kernel<<<(NG * NC + tb - 1) / tb, tb, 0, stream>>>(pooled, batch, Wlin, bl, out, N);
}

// Round 7
// 236.384 us; speedup vs baseline: 1.1145x; 1.1145x over previous
//
#include <hip/hip_runtime.h>

#define D 128
#define NG 64
#define NC 16
#define NEG 0.1f

typedef __attribute__((ext_vector_type(8))) short bf16x8;
typedef __attribute__((ext_vector_type(4))) float f32x4;

// ---------- bf16 <-> fp32 helpers (bf16 stored as ushort, packed pairs in uint) ----------
__device__ __forceinline__ float bf2f(unsigned int u16) {
    union { unsigned int i; float f; } c;
    c.i = u16 << 16;
    return c.f;
}
__device__ __forceinline__ unsigned short f2bf(float f) {
    union { float f; unsigned int i; } c;
    c.f = f;
    unsigned int i = c.i;
    unsigned int r = (i + 0x7FFFu + ((i >> 16) & 1u)) >> 16;  // RNE
    return (unsigned short)r;
}

// ---------------- fused prep + layer-1 GEMM ----------------
// blocks [0, gb):           layer-1 MFMA GEMM (A = x f32; W1 converted in-block to the
//                           fragment-order bf16 image directly in LDS — no global Wf1,
//                           no producer/consumer ordering needed inside the launch).
// blocks [gb, gb+8):        W2 -> Wf2 fragment-order bf16 image (consumed by gemm2 later).
// blocks [gb+8, gb+40):     zero pooled.
// blocks [gb+40, ...):      degree histogram over dst.
// gemm1 (~12us) runs concurrently with the 600K-edge histogram instead of after the CSR chain.
__global__ __launch_bounds__(256) void prep_gemm1_kernel(
        const float* __restrict__ x, const float* __restrict__ W1,
        unsigned int* __restrict__ C, int gb,
        const float* __restrict__ W2, unsigned short* __restrict__ Wf2,
        float* __restrict__ pooled,
        const int* __restrict__ dst, int* __restrict__ deg, int E, int N) {
    __shared__ uint4 Ws[2048];  // 32 KB, fragment-order image (gemm blocks only)
    int b = blockIdx.x;
    int tid = threadIdx.x;
    if (b < gb) {
        // ---- layer-1 GEMM, W1 image built in-block ----
        int w = tid >> 6, lane = tid & 63;
        int quad = lane >> 4, m16 = lane & 15;
        int rowstart = b * 64;
#pragma unroll
        for (int i = 0; i < 8; i++) {
            int fid = tid + 256 * i;
            int fm = fid & 15;
            int fquad = (fid >> 4) & 3;
            int fkc = (fid >> 6) & 3;
            int ft = fid >> 8;
            int n = ft * 16 + fm;
            int k0 = fkc * 32 + fquad * 8;
            unsigned short r[8];
#pragma unroll
            for (int j = 0; j < 8; j++) r[j] = f2bf(W1[(k0 + j) * 128 + n]);
            uint4 v;
            v.x = (unsigned int)r[0] | ((unsigned int)r[1] << 16);
            v.y = (unsigned int)r[2] | ((unsigned int)r[3] << 16);
            v.z = (unsigned int)r[4] | ((unsigned int)r[5] << 16);
            v.w = (unsigned int)r[6] | ((unsigned int)r[7] << 16);
            Ws[fid] = v;
        }

        int arow = rowstart + 16 * w + m16;
        bool valid = arow < N;
        bf16x8 af[4];
#pragma unroll
        for (int kc = 0; kc < 4; kc++) {
            float4 f0 = make_float4(0.f, 0.f, 0.f, 0.f), f1 = f0;
            if (valid) {
                const float4* p = (const float4*)(x + (size_t)arow * 128 + kc * 32 + quad * 8);
                f0 = p[0];
                f1 = p[1];
            }
            bf16x8 a;
            a[0] = (short)f2bf(f0.x); a[1] = (short)f2bf(f0.y);
            a[2] = (short)f2bf(f0.z); a[3] = (short)f2bf(f0.w);
            a[4] = (short)f2bf(f1.x); a[5] = (short)f2bf(f1.y);
            a[6] = (short)f2bf(f1.z); a[7] = (short)f2bf(f1.w);
            af[kc] = a;
        }
        __syncthreads();

        f32x4 acc[8];
#pragma unroll
        for (int t = 0; t < 8; t++) acc[t] = (f32x4){0.f, 0.f, 0.f, 0.f};
#pragma unroll
        for (int t = 0; t < 8; t++) {
#pragma unroll
            for (int kc = 0; kc < 4; kc++) {
                bf16x8 bh = *(const bf16x8*)&Ws[(((t * 4 + kc) * 4 + quad) * 16 + m16)];
                acc[t] = __builtin_amdgcn_mfma_f32_16x16x32_bf16(af[kc], bh, acc[t], 0, 0, 0);
            }
        }
#pragma unroll
        for (int t = 0; t < 8; t++) {
#pragma unroll
            for (int r = 0; r < 4; r++) {
                int row = rowstart + 16 * w + quad * 4 + r;
                unsigned int us = f2bf(acc[t][r]);
                unsigned int other = (unsigned int)__shfl_xor((int)us, 1);
                if (((m16 & 1) == 0) && row < N)
                    C[(size_t)row * 64 + t * 8 + (m16 >> 1)] = us | (other << 16);
            }
        }
    } else {
        int bb = b - gb;
        if (bb < 8) {
            // W2 -> fragment-order bf16 image (global; gemm2 consumes next-next launch)
            int fid = bb * 256 + tid;
            int m = fid & 15;
            int quad = (fid >> 4) & 3;
            int kc = (fid >> 6) & 3;
            int t = fid >> 8;
            int n = t * 16 + m;
            int k0 = kc * 32 + quad * 8;
            unsigned short r[8];
#pragma unroll
            for (int j = 0; j < 8; j++) r[j] = f2bf(W2[(k0 + j) * 128 + n]);
            uint4 v;
            v.x = (unsigned int)r[0] | ((unsigned int)r[1] << 16);
            v.y = (unsigned int)r[2] | ((unsigned int)r[3] << 16);
            v.z = (unsigned int)r[4] | ((unsigned int)r[5] << 16);
            v.w = (unsigned int)r[6] | ((unsigned int)r[7] << 16);
            ((uint4*)Wf2)[fid] = v;
        } else if (bb < 40) {
            pooled[(bb - 8) * 256 + tid] = 0.f;
        } else {
            int e = (bb - 40) * 256 + tid;
            if (e < E) atomicAdd(&deg[dst[e]], 1);
        }
    }
}

// ---------------- scan stage 1 (+ dinv fold) ----------------
__global__ void scan_block_kernel(const int* __restrict__ deg, int* __restrict__ scan1,
                                  int* __restrict__ blocksum, float* __restrict__ dinv, int N) {
    __shared__ int sm[256];
    int tid = threadIdx.x;
    int i = blockIdx.x * 256 + tid;
    int v = (i < N) ? deg[i] : 0;
    if (i < N) dinv[i] = 1.0f / sqrtf((float)v + 1.0f);
    sm[tid] = v;
    __syncthreads();
    for (int off = 1; off < 256; off <<= 1) {
        int t = (tid >= off) ? sm[tid - off] : 0;
        __syncthreads();
        sm[tid] += t;
        __syncthreads();
    }
    if (i < N) scan1[i] = sm[tid];  // inclusive
    if (tid == 255) blocksum[blockIdx.x] = sm[255];
}

// ---------------- finalize: ptr = exclusive prefix; fill seeded with ptr (scatter cursor) ----
// (nscan <= 256 guaranteed: N <= 65536).
__global__ void finalize_ptr_kernel(const int* __restrict__ deg, const int* __restrict__ scan1,
                                    const int* __restrict__ blocksum, int* __restrict__ ptr,
                                    int* __restrict__ fill, int nb, int N, int E) {
    __shared__ int sm[256];
    int tid = threadIdx.x;
    int v = (tid < nb) ? blocksum[tid] : 0;
    sm[tid] = v;
    __syncthreads();
    for (int off = 1; off < 256; off <<= 1) {
        int t = (tid >= off) ? sm[tid - off] : 0;
        __syncthreads();
        sm[tid] += t;
        __syncthreads();
    }
    int blockoff = (blockIdx.x > 0) ? sm[blockIdx.x - 1] : 0;  // exclusive prefix for this block
    int i = blockIdx.x * 256 + tid;
    if (i < N) {
        int p = scan1[i] - deg[i] + blockoff;
        ptr[i] = p;
        fill[i] = p;  // scatter's cursor starts at ptr -> scatter needs no ptr[d] read
        if (i == N - 1) ptr[N] = E;
    }
}

// ---------------- scatter edges into CSR by dst; packed (src, coef) int2 ----------------
// coef precomputed HERE (R2/R3 lesson: per-edge dinv loads inside combine's gather loop hurt).
// fill[] pre-seeded with ptr -> position comes straight from the atomic (one less random read).
__global__ void scatter_kernel(const int* __restrict__ src, const int* __restrict__ dst,
                               int* __restrict__ fill, const float* __restrict__ dinv,
                               int2* __restrict__ csr_edge, int E) {
    int e = blockIdx.x * blockDim.x + threadIdx.x;
    if (e < E) {
        int d = dst[e];
        int s = src[e];
        int pos = atomicAdd(&fill[d], 1);
        float coef = dinv[s] * dinv[d];
        csr_edge[pos] = make_int2(s, __float_as_int(coef));
    }
}

// ---------------- MFMA GEMM (layer 2): C[N,128](packed bf16) = A[N,128] @ W ----------------
// A is packed bf16; W staged from the prebuilt fragment-order image.
__global__ __launch_bounds__(256) void gemm_mfma_kernel(const unsigned short* __restrict__ Ag,
                                                        const uint4* __restrict__ Wf,
                                                        unsigned int* __restrict__ C, int N) {
    __shared__ uint4 Ws[2048];  // 32 KB, fragment-order image
    int tid = threadIdx.x;
    int w = tid >> 6, lane = tid & 63;
    int quad = lane >> 4, m = lane & 15;
    int rowstart = blockIdx.x * 64;

#pragma unroll
    for (int i = 0; i < 8; i++) Ws[tid + 256 * i] = Wf[tid + 256 * i];

    int arow = rowstart + 16 * w + m;
    bool valid = arow < N;
    bf16x8 af[4];
#pragma unroll
    for (int kc = 0; kc < 4; kc++) {
        bf16x8 a;
#pragma unroll
        for (int j = 0; j < 8; j++) a[j] = 0;
        if (valid) a = *(const bf16x8*)(Ag + (size_t)arow * 128 + kc * 32 + quad * 8);
        af[kc] = a;
    }
    __syncthreads();

    f32x4 acc[8];
#pragma unroll
    for (int t = 0; t < 8; t++) acc[t] = (f32x4){0.f, 0.f, 0.f, 0.f};

#pragma unroll
    for (int t = 0; t < 8; t++) {
#pragma unroll
        for (int kc = 0; kc < 4; kc++) {
            bf16x8 bh = *(const bf16x8*)&Ws[(((t * 4 + kc) * 4 + quad) * 16 + m)];
            acc[t] = __builtin_amdgcn_mfma_f32_16x16x32_bf16(af[kc], bh, acc[t], 0, 0, 0);
        }
    }

#pragma unroll
    for (int t = 0; t < 8; t++) {
#pragma unroll
        for (int r = 0; r < 4; r++) {
            int row = rowstart + 16 * w + quad * 4 + r;
            unsigned int us = f2bf(acc[t][r]);
            unsigned int other = (unsigned int)__shfl_xor((int)us, 1);
            if (((m & 1) == 0) && row < N)
                C[(size_t)row * 64 + t * 8 + (m >> 1)] = us | (other << 16);
        }
    }
}

// ---------------- gather + self-loop + bias + leaky_relu (R1-verified optimum) ----------------
// 4 consecutive nodes per wave, one node per 16-lane quarter; wave's CSR slice staged to a
// wave-private LDS strip (int2 src+coef, broadcast ds_read); 4-deep unrolled 256B gathers +
// serial tail (R5: clamped groups regress; R6: 8 nodes/wave regresses).
#define ACC8(v, c)                                                         \
    a0 += bf2f((v).x & 0xffffu) * (c); a1 += bf2f((v).x >> 16) * (c);      \
    a2 += bf2f((v).y & 0xffffu) * (c); a3 += bf2f((v).y >> 16) * (c);      \
    a4 += bf2f((v).z & 0xffffu) * (c); a5 += bf2f((v).z >> 16) * (c);      \
    a6 += bf2f((v).w & 0xffffu) * (c); a7 += bf2f((v).w >> 16) * (c);

__global__ __launch_bounds__(256) void combine_kernel(const uint4* __restrict__ h4,
                                                      const int* __restrict__ ptr,
                                                      const int2* __restrict__ csr_edge,
                                                      const float* __restrict__ dinv,
                                                      const float* __restrict__ b,
                                                      uint4* __restrict__ out4, int N) {
    __shared__ int2 smeta[4][64];  // 2 KB, one strip per wave
    int wave = threadIdx.x >> 6;
    int lane = threadIdx.x & 63;
    int q = lane >> 4;
    int l16 = lane & 15;
    int nb = blockIdx.x * 16 + wave * 4;  // first node of this wave
    if (nb >= N) return;                  // wave-uniform exit; kernel uses no barriers
    int node = nb + q;
    bool valid = node < N;

    int wlo = ptr[nb];
    int whi = ptr[min(nb + 4, N)];
    int lo = valid ? ptr[node] : 0;
    int hi = valid ? ptr[node + 1] : 0;

    // prefetch self row / dinv / bias — overlaps the gather loop
    float di = valid ? dinv[node] : 0.f;
    uint4 sv = valid ? h4[(size_t)node * 16 + l16] : make_uint4(0u, 0u, 0u, 0u);
    float4 bv0 = ((const float4*)b)[l16 * 2];
    float4 bv1 = ((const float4*)b)[l16 * 2 + 1];

    float a0 = 0.f, a1 = 0.f, a2 = 0.f, a3 = 0.f, a4 = 0.f, a5 = 0.f, a6 = 0.f, a7 = 0.f;

#pragma unroll 1
    for (int base = wlo; base < whi; base += 64) {
        // cooperative, coalesced stage of the wave's next 64 edges (all 64 lanes)
        if (base + lane < whi) smeta[wave][lane] = csr_edge[base + lane];
        // wave-private strip: same-wave DS ordering (compiler lgkmcnt) suffices, no barrier.
        int s = max(lo, base);
        int e = min(hi, base + 64);
        int j = s;
#pragma unroll 1
        for (; j + 3 < e; j += 4) {
            int k = j - base;
            int2 e0 = smeta[wave][k];      // 16 lanes same addr -> LDS broadcast
            int2 e1 = smeta[wave][k + 1];
            int2 e2 = smeta[wave][k + 2];
            int2 e3 = smeta[wave][k + 3];
            uint4 v0 = h4[(size_t)e0.x * 16 + l16];
            uint4 v1 = h4[(size_t)e1.x * 16 + l16];
            uint4 v2 = h4[(size_t)e2.x * 16 + l16];
            uint4 v3 = h4[(size_t)e3.x * 16 + l16];
            float c0 = __int_as_float(e0.y);
            float c1 = __int_as_float(e1.y);
            float c2 = __int_as_float(e2.y);
            float c3 = __int_as_float(e3.y);
            ACC8(v0, c0)
            ACC8(v1, c1)
            ACC8(v2, c2)
            ACC8(v3, c3)
        }
#pragma unroll 1
        for (; j < e; j++) {
            int k = j - base;
            int2 e0 = smeta[wave][k];
            uint4 v0 = h4[(size_t)e0.x * 16 + l16];
            float c0 = __int_as_float(e0.y);
            ACC8(v0, c0)
        }
    }

    if (!valid) return;
    float dd = di * di;
    float v0 = a0 + bf2f(sv.x & 0xffffu) * dd + bv0.x;
    float v1 = a1 + bf2f(sv.x >> 16) * dd + bv0.y;
    float v2 = a2 + bf2f(sv.y & 0xffffu) * dd + bv0.z;
    float v3 = a3 + bf2f(sv.y >> 16) * dd + bv0.w;
    float v4 = a4 + bf2f(sv.z & 0xffffu) * dd + bv1.x;
    float v5 = a5 + bf2f(sv.z >> 16) * dd + bv1.y;
    float v6 = a6 + bf2f(sv.w & 0xffffu) * dd + bv1.z;
    float v7 = a7 + bf2f(sv.w >> 16) * dd + bv1.w;
    v0 = (v0 >= 0.f) ? v0 : NEG * v0;
    v1 = (v1 >= 0.f) ? v1 : NEG * v1;
    v2 = (v2 >= 0.f) ? v2 : NEG * v2;
    v3 = (v3 >= 0.f) ? v3 : NEG * v3;
    v4 = (v4 >= 0.f) ? v4 : NEG * v4;
    v5 = (v5 >= 0.f) ? v5 : NEG * v5;
    v6 = (v6 >= 0.f) ? v6 : NEG * v6;
    v7 = (v7 >= 0.f) ? v7 : NEG * v7;
    uint4 pv;
    pv.x = (unsigned int)f2bf(v0) | ((unsigned int)f2bf(v1) << 16);
    pv.y = (unsigned int)f2bf(v2) | ((unsigned int)f2bf(v3) << 16);
    pv.z = (unsigned int)f2bf(v4) | ((unsigned int)f2bf(v5) << 16);
    pv.w = (unsigned int)f2bf(v6) | ((unsigned int)f2bf(v7) << 16);
    out4[(size_t)node * 16 + l16] = pv;
}

// ---------------- pool: node-parallel chunked accumulate (batch sorted) ----------------
// R2/R3 lesson: do NOT fuse pooling into combine — 1.6M device-scope atomics onto 8KB
// serialized at the coherence point and cost ~100us.
#define PROWS 128
__global__ void pool_accum_kernel(const unsigned int* __restrict__ a2,
                                  const int* __restrict__ batch,
                                  float* __restrict__ pooled, int N) {
    int wave = threadIdx.x >> 6;
    int lane = threadIdx.x & 63;
    int start = blockIdx.x * PROWS;
    int end = start + PROWS;
    if (end > N) end = N;
    float s0 = 0.f, s1 = 0.f;
    int curg = -1;
    for (int r = start + wave; r < end; r += 4) {
        int g = batch[r];  // wave-uniform (sorted batch)
        if (g != curg) {
            if (curg >= 0) {
                atomicAdd(&pooled[curg * D + 2 * lane], s0);
                atomicAdd(&pooled[curg * D + 2 * lane + 1], s1);
            }
            curg = g;
            s0 = 0.f;
            s1 = 0.f;
        }
        unsigned int v = a2[(size_t)r * 64 + lane];
        s0 += bf2f(v & 0xffffu);
        s1 += bf2f(v >> 16);
    }
    if (curg >= 0) {
        atomicAdd(&pooled[curg * D + 2 * lane], s0);
        atomicAdd(&pooled[curg * D + 2 * lane + 1], s1);
    }
}

// ---------------- final linear: out[g,c] = (sum[g]/cnt[g]) . Wl[:,c] + bl[c] ----------------
__global__ void final_kernel(const float* __restrict__ pooled, const int* __restrict__ batch,
                             const float* __restrict__ Wl, const float* __restrict__ bl,
                             float* __restrict__ out, int N) {
    int t = blockIdx.x * blockDim.x + threadIdx.x;
    if (t >= NG * NC) return;
    int g = t >> 4, c = t & 15;
    int l = 0, h = N;
    while (l < h) { int m = (l + h) >> 1; if (batch[m] < g) l = m + 1; else h = m; }
    int lo = l;
    h = N;
    while (l < h) { int m = (l + h) >> 1; if (batch[m] < g + 1) l = m + 1; else h = m; }
    int cnt = l - lo;
    float inv = 1.0f / (float)(cnt > 0 ? cnt : 1);
    float dot = 0.f;
    for (int k = 0; k < D; k++) dot += pooled[g * D + k] * Wl[k * NC + c];
    out[t] = dot * inv + bl[c];
}

extern "C" void kernel_launch(void* const* d_in, const int* in_sizes, int n_in,
                              void* d_out, int out_size, void* d_ws, size_t ws_size,
                              hipStream_t stream) {
    const float* x = (const float*)d_in[0];
    const int* ei = (const int*)d_in[1];
    const int* batch = (const int*)d_in[2];
    const float* W1 = (const float*)d_in[3];
    const float* b1 = (const float*)d_in[4];
    const float* W2 = (const float*)d_in[5];
    const float* b2 = (const float*)d_in[6];
    const float* Wlin = (const float*)d_in[7];
    const float* bl = (const float*)d_in[8];
    float* out = (float*)d_out;

    int N = in_sizes[0] / D;
    int E = in_sizes[1] / 2;
    const int* src = ei;
    const int* dst = ei + E;

    // workspace layout (float units). 128x128 bf16 image = 16384 shorts = 8192 floats.
    float* ws = (float*)d_ws;
    size_t o = 0;
    unsigned int* bufA = (unsigned int*)(ws + o); o += (size_t)N * 64;  // 12.8 MB
    unsigned int* bufB = (unsigned int*)(ws + o); o += (size_t)N * 64;  // 12.8 MB
    int* deg = (int*)(ws + o);      o += N;       // zeroed by memset below
    int* fill = (int*)(ws + o);     o += N;       // seeded with ptr inside finalize
    float* dinv = ws + o;           o += N;
    int* scan1 = (int*)(ws + o);    o += N;
    int* blocksum = (int*)(ws + o); o += 256;
    int* csr_ptr = (int*)(ws + o);  o += (N + 4);
    int2* csr_edge = (int2*)(ws + o); o += (size_t)2 * E;
    float* pooled = ws + o;         o += NG * D;
    unsigned short* Wf2 = (unsigned short*)(ws + o); o += 8192;  // fragment-order bf16 image

    hipMemsetAsync(deg, 0, (size_t)N * sizeof(int), stream);

    int tb = 256;
    int nscan = (N + 255) / 256;
    int gblocks = (N + 63) / 64;
    int cblocks = (N + 15) / 16;
    int eblocks = (E + 255) / 256;

    // fused: layer-1 GEMM || {Wf2 image, pooled zero, degree histogram}
    prep_gemm1_kernel<<<gblocks + 40 + eblocks, 256, 0, stream>>>(
        x, W1, (unsigned int*)bufA, gblocks, W2, Wf2, pooled, dst, deg, E, N);
    scan_block_kernel<<<nscan, 256, 0, stream>>>(deg, scan1, blocksum, dinv, N);
    finalize_ptr_kernel<<<nscan, 256, 0, stream>>>(deg, scan1, blocksum, csr_ptr, fill,
                                                   nscan, N, E);
    scatter_kernel<<<(E + tb - 1) / tb, tb, 0, stream>>>(src, dst, fill, dinv,
                                                         csr_edge, E);

    // layer 1 combine (gemm1 already done in the fused launch)
    combine_kernel<<<cblocks, 256, 0, stream>>>((const uint4*)bufA, csr_ptr, csr_edge,
                                                dinv, b1, (uint4*)bufB, N);
    // layer 2
    gemm_mfma_kernel<<<gblocks, 256, 0, stream>>>((const unsigned short*)bufB,
                                                  (const uint4*)Wf2,
                                                  (unsigned int*)bufA, N);
    combine_kernel<<<cblocks, 256, 0, stream>>>((const uint4*)bufA, csr_ptr, csr_edge,
                                                dinv, b2, (uint4*)bufB, N);
    // pool + classifier
    pool_accum_kernel<<<(N + PROWS - 1) / PROWS, 256, 0, stream>>>(bufB, batch, pooled, N);
    final_kernel<<<(NG * NC + tb - 1) / tb, tb, 0, stream>>>(pooled, batch, Wlin, bl, out, N);
}

// Round 8
// 227.307 us; speedup vs baseline: 1.1590x; 1.0399x over previous
//
#include <hip/hip_runtime.h>

#define D 128
#define NG 64
#define NC 16
#define NEG 0.1f

typedef __attribute__((ext_vector_type(8))) short bf16x8;
typedef __attribute__((ext_vector_type(4))) float f32x4;

// ---------- bf16 <-> fp32 helpers (bf16 stored as ushort, packed pairs in uint) ----------
__device__ __forceinline__ float bf2f(unsigned int u16) {
    union { unsigned int i; float f; } c;
    c.i = u16 << 16;
    return c.f;
}
__device__ __forceinline__ unsigned short f2bf(float f) {
    union { float f; unsigned int i; } c;
    c.f = f;
    unsigned int i = c.i;
    unsigned int r = (i + 0x7FFFu + ((i >> 16) & 1u)) >> 16;  // RNE
    return (unsigned short)r;
}

// ---------------- fused prep + layer-1 GEMM (R7-verified) ----------------
// blocks [0, gb): layer-1 MFMA GEMM (W1 image built in-block in LDS).
// blocks [gb, gb+8): W2 -> Wf2 fragment-order image. [gb+8, gb+40): zero pooled.
// [gb+40, ...): degree histogram. gemm1 runs concurrently with the histogram.
__global__ __launch_bounds__(256) void prep_gemm1_kernel(
        const float* __restrict__ x, const float* __restrict__ W1,
        unsigned int* __restrict__ C, int gb,
        const float* __restrict__ W2, unsigned short* __restrict__ Wf2,
        float* __restrict__ pooled,
        const int* __restrict__ dst, int* __restrict__ deg, int E, int N) {
    __shared__ uint4 Ws[2048];  // 32 KB, fragment-order image (gemm blocks only)
    int b = blockIdx.x;
    int tid = threadIdx.x;
    if (b < gb) {
        int w = tid >> 6, lane = tid & 63;
        int quad = lane >> 4, m16 = lane & 15;
        int rowstart = b * 64;
#pragma unroll
        for (int i = 0; i < 8; i++) {
            int fid = tid + 256 * i;
            int fm = fid & 15;
            int fquad = (fid >> 4) & 3;
            int fkc = (fid >> 6) & 3;
            int ft = fid >> 8;
            int n = ft * 16 + fm;
            int k0 = fkc * 32 + fquad * 8;
            unsigned short r[8];
#pragma unroll
            for (int j = 0; j < 8; j++) r[j] = f2bf(W1[(k0 + j) * 128 + n]);
            uint4 v;
            v.x = (unsigned int)r[0] | ((unsigned int)r[1] << 16);
            v.y = (unsigned int)r[2] | ((unsigned int)r[3] << 16);
            v.z = (unsigned int)r[4] | ((unsigned int)r[5] << 16);
            v.w = (unsigned int)r[6] | ((unsigned int)r[7] << 16);
            Ws[fid] = v;
        }

        int arow = rowstart + 16 * w + m16;
        bool valid = arow < N;
        bf16x8 af[4];
#pragma unroll
        for (int kc = 0; kc < 4; kc++) {
            float4 f0 = make_float4(0.f, 0.f, 0.f, 0.f), f1 = f0;
            if (valid) {
                const float4* p = (const float4*)(x + (size_t)arow * 128 + kc * 32 + quad * 8);
                f0 = p[0];
                f1 = p[1];
            }
            bf16x8 a;
            a[0] = (short)f2bf(f0.x); a[1] = (short)f2bf(f0.y);
            a[2] = (short)f2bf(f0.z); a[3] = (short)f2bf(f0.w);
            a[4] = (short)f2bf(f1.x); a[5] = (short)f2bf(f1.y);
            a[6] = (short)f2bf(f1.z); a[7] = (short)f2bf(f1.w);
            af[kc] = a;
        }
        __syncthreads();

        f32x4 acc[8];
#pragma unroll
        for (int t = 0; t < 8; t++) acc[t] = (f32x4){0.f, 0.f, 0.f, 0.f};
#pragma unroll
        for (int t = 0; t < 8; t++) {
#pragma unroll
            for (int kc = 0; kc < 4; kc++) {
                bf16x8 bh = *(const bf16x8*)&Ws[(((t * 4 + kc) * 4 + quad) * 16 + m16)];
                acc[t] = __builtin_amdgcn_mfma_f32_16x16x32_bf16(af[kc], bh, acc[t], 0, 0, 0);
            }
        }
#pragma unroll
        for (int t = 0; t < 8; t++) {
#pragma unroll
            for (int r = 0; r < 4; r++) {
                int row = rowstart + 16 * w + quad * 4 + r;
                unsigned int us = f2bf(acc[t][r]);
                unsigned int other = (unsigned int)__shfl_xor((int)us, 1);
                if (((m16 & 1) == 0) && row < N)
                    C[(size_t)row * 64 + t * 8 + (m16 >> 1)] = us | (other << 16);
            }
        }
    } else {
        int bb = b - gb;
        if (bb < 8) {
            int fid = bb * 256 + tid;
            int m = fid & 15;
            int quad = (fid >> 4) & 3;
            int kc = (fid >> 6) & 3;
            int t = fid >> 8;
            int n = t * 16 + m;
            int k0 = kc * 32 + quad * 8;
            unsigned short r[8];
#pragma unroll
            for (int j = 0; j < 8; j++) r[j] = f2bf(W2[(k0 + j) * 128 + n]);
            uint4 v;
            v.x = (unsigned int)r[0] | ((unsigned int)r[1] << 16);
            v.y = (unsigned int)r[2] | ((unsigned int)r[3] << 16);
            v.z = (unsigned int)r[4] | ((unsigned int)r[5] << 16);
            v.w = (unsigned int)r[6] | ((unsigned int)r[7] << 16);
            ((uint4*)Wf2)[fid] = v;
        } else if (bb < 40) {
            pooled[(bb - 8) * 256 + tid] = 0.f;
        } else {
            int e = (bb - 40) * 256 + tid;
            if (e < E) atomicAdd(&deg[dst[e]], 1);
        }
    }
}

// ---------------- scan stage 1 (+ dinv fold) ----------------
__global__ void scan_block_kernel(const int* __restrict__ deg, int* __restrict__ scan1,
                                  int* __restrict__ blocksum, float* __restrict__ dinv, int N) {
    __shared__ int sm[256];
    int tid = threadIdx.x;
    int i = blockIdx.x * 256 + tid;
    int v = (i < N) ? deg[i] : 0;
    if (i < N) dinv[i] = 1.0f / sqrtf((float)v + 1.0f);
    sm[tid] = v;
    __syncthreads();
    for (int off = 1; off < 256; off <<= 1) {
        int t = (tid >= off) ? sm[tid - off] : 0;
        __syncthreads();
        sm[tid] += t;
        __syncthreads();
    }
    if (i < N) scan1[i] = sm[tid];  // inclusive
    if (tid == 255) blocksum[blockIdx.x] = sm[255];
}

// ---------------- finalize: ptr = exclusive prefix; fill seeded with ptr (scatter cursor) ----
__global__ void finalize_ptr_kernel(const int* __restrict__ deg, const int* __restrict__ scan1,
                                    const int* __restrict__ blocksum, int* __restrict__ ptr,
                                    int* __restrict__ fill, int nb, int N, int E) {
    __shared__ int sm[256];
    int tid = threadIdx.x;
    int v = (tid < nb) ? blocksum[tid] : 0;
    sm[tid] = v;
    __syncthreads();
    for (int off = 1; off < 256; off <<= 1) {
        int t = (tid >= off) ? sm[tid - off] : 0;
        __syncthreads();
        sm[tid] += t;
        __syncthreads();
    }
    int blockoff = (blockIdx.x > 0) ? sm[blockIdx.x - 1] : 0;
    int i = blockIdx.x * 256 + tid;
    if (i < N) {
        int p = scan1[i] - deg[i] + blockoff;
        ptr[i] = p;
        fill[i] = p;  // scatter cursor
        if (i == N - 1) ptr[N] = E;
    }
}

// ---------------- scatter edges into CSR by dst; packed (src, coef) int2 ----------------
__global__ void scatter_kernel(const int* __restrict__ src, const int* __restrict__ dst,
                               int* __restrict__ fill, const float* __restrict__ dinv,
                               int2* __restrict__ csr_edge, int E) {
    int e = blockIdx.x * blockDim.x + threadIdx.x;
    if (e < E) {
        int d = dst[e];
        int s = src[e];
        int pos = atomicAdd(&fill[d], 1);
        float coef = dinv[s] * dinv[d];
        csr_edge[pos] = make_int2(s, __float_as_int(coef));
    }
}

#define ACC8(v, c)                                                         \
    a0 += bf2f((v).x & 0xffffu) * (c); a1 += bf2f((v).x >> 16) * (c);      \
    a2 += bf2f((v).y & 0xffffu) * (c); a3 += bf2f((v).y >> 16) * (c);      \
    a4 += bf2f((v).z & 0xffffu) * (c); a5 += bf2f((v).z >> 16) * (c);      \
    a6 += bf2f((v).w & 0xffffu) * (c); a7 += bf2f((v).w >> 16) * (c);

// ---------------- FUSED combine(layer1) + gemm2 ----------------
// Phase 1 (R1-verified combine): 4 nodes/wave, 16 lanes/row, LDS edge-strip broadcast,
// 4-deep gathers + serial tail. Result h1 rows (post bias+leakyrelu) are RNE-rounded to
// bf16 and written to a padded LDS row tile [16][272B] (row stride 68 uints -> max 2-way
// bank aliasing, free). NO global h1 store.
// Phase 2 (after one barrier): 16x128 @ 128x128 MFMA tile. A-fragments from the LDS row
// tile; B-fragments read directly from the global fragment-order Wf2 image (coalesced,
// L2-resident; not LDS-staged to keep occupancy). Output = h1@W2 rows -> C (packed bf16).
// Invalid tail rows: LDS garbage stays in its own output row; store masked by row<N.
__global__ __launch_bounds__(256) void combine_gemm_kernel(
        const uint4* __restrict__ h4,       // G1 = x@W1 rows (packed bf16)
        const int* __restrict__ ptr,
        const int2* __restrict__ csr_edge,
        const float* __restrict__ dinv,
        const float* __restrict__ b,        // b1
        const uint4* __restrict__ Wf2,      // fragment-order W2 image
        unsigned int* __restrict__ C,       // out: (h1 @ W2) rows, packed bf16
        int N) {
    __shared__ int2 smeta[4][64];           // 2 KB edge strips
    __shared__ unsigned int rowt[16 * 68];  // 16 rows x 272 B padded h1 tile (4.25 KB)
    int wave = threadIdx.x >> 6;
    int lane = threadIdx.x & 63;
    int q = lane >> 4;
    int l16 = lane & 15;
    int bb = blockIdx.x * 16;
    int nb = bb + wave * 4;
    int node = nb + q;
    bool valid = node < N;

    if (nb < N) {  // predicated (no return: barrier below needs all waves)
        int wlo = ptr[nb];
        int whi = ptr[min(nb + 4, N)];
        int lo = valid ? ptr[node] : 0;
        int hi = valid ? ptr[node + 1] : 0;

        float di = valid ? dinv[node] : 0.f;
        uint4 sv = valid ? h4[(size_t)node * 16 + l16] : make_uint4(0u, 0u, 0u, 0u);
        float4 bv0 = ((const float4*)b)[l16 * 2];
        float4 bv1 = ((const float4*)b)[l16 * 2 + 1];

        float a0 = 0.f, a1 = 0.f, a2 = 0.f, a3 = 0.f, a4 = 0.f, a5 = 0.f, a6 = 0.f, a7 = 0.f;

#pragma unroll 1
        for (int base = wlo; base < whi; base += 64) {
            if (base + lane < whi) smeta[wave][lane] = csr_edge[base + lane];
            // wave-private strip: same-wave DS ordering suffices, no barrier
            int s = max(lo, base);
            int e = min(hi, base + 64);
            int j = s;
#pragma unroll 1
            for (; j + 3 < e; j += 4) {
                int k = j - base;
                int2 e0 = smeta[wave][k];
                int2 e1 = smeta[wave][k + 1];
                int2 e2 = smeta[wave][k + 2];
                int2 e3 = smeta[wave][k + 3];
                uint4 v0 = h4[(size_t)e0.x * 16 + l16];
                uint4 v1 = h4[(size_t)e1.x * 16 + l16];
                uint4 v2 = h4[(size_t)e2.x * 16 + l16];
                uint4 v3 = h4[(size_t)e3.x * 16 + l16];
                float c0 = __int_as_float(e0.y);
                float c1 = __int_as_float(e1.y);
                float c2 = __int_as_float(e2.y);
                float c3 = __int_as_float(e3.y);
                ACC8(v0, c0)
                ACC8(v1, c1)
                ACC8(v2, c2)
                ACC8(v3, c3)
            }
#pragma unroll 1
            for (; j < e; j++) {
                int k = j - base;
                int2 e0 = smeta[wave][k];
                uint4 v0 = h4[(size_t)e0.x * 16 + l16];
                float c0 = __int_as_float(e0.y);
                ACC8(v0, c0)
            }
        }

        if (valid) {
            float dd = di * di;
            float v0 = a0 + bf2f(sv.x & 0xffffu) * dd + bv0.x;
            float v1 = a1 + bf2f(sv.x >> 16) * dd + bv0.y;
            float v2 = a2 + bf2f(sv.y & 0xffffu) * dd + bv0.z;
            float v3 = a3 + bf2f(sv.y >> 16) * dd + bv0.w;
            float v4 = a4 + bf2f(sv.z & 0xffffu) * dd + bv1.x;
            float v5 = a5 + bf2f(sv.z >> 16) * dd + bv1.y;
            float v6 = a6 + bf2f(sv.w & 0xffffu) * dd + bv1.z;
            float v7 = a7 + bf2f(sv.w >> 16) * dd + bv1.w;
            v0 = (v0 >= 0.f) ? v0 : NEG * v0;
            v1 = (v1 >= 0.f) ? v1 : NEG * v1;
            v2 = (v2 >= 0.f) ? v2 : NEG * v2;
            v3 = (v3 >= 0.f) ? v3 : NEG * v3;
            v4 = (v4 >= 0.f) ? v4 : NEG * v4;
            v5 = (v5 >= 0.f) ? v5 : NEG * v5;
            v6 = (v6 >= 0.f) ? v6 : NEG * v6;
            v7 = (v7 >= 0.f) ? v7 : NEG * v7;
            unsigned int* p = &rowt[(wave * 4 + q) * 68 + l16 * 4];
            p[0] = (unsigned int)f2bf(v0) | ((unsigned int)f2bf(v1) << 16);
            p[1] = (unsigned int)f2bf(v2) | ((unsigned int)f2bf(v3) << 16);
            p[2] = (unsigned int)f2bf(v4) | ((unsigned int)f2bf(v5) << 16);
            p[3] = (unsigned int)f2bf(v6) | ((unsigned int)f2bf(v7) << 16);
        }
    }
    __syncthreads();

    // ---- phase 2: 16x128 GEMM tile, h1(LDS) @ W2(global image) ----
#pragma unroll
    for (int tt = 0; tt < 2; tt++) {
        int t = wave * 2 + tt;
        f32x4 acc = (f32x4){0.f, 0.f, 0.f, 0.f};
#pragma unroll
        for (int kc = 0; kc < 4; kc++) {
            // A: row m=l16, k = kc*32 + q*8 + j  (uint offset: kc*16 + q*4)
            bf16x8 a = *(const bf16x8*)&rowt[l16 * 68 + kc * 16 + q * 4];
            bf16x8 bh = *(const bf16x8*)&Wf2[((t * 4 + kc) * 4 + q) * 16 + l16];
            acc = __builtin_amdgcn_mfma_f32_16x16x32_bf16(a, bh, acc, 0, 0, 0);
        }
#pragma unroll
        for (int r = 0; r < 4; r++) {
            int row = bb + q * 4 + r;
            unsigned int us = f2bf(acc[r]);
            unsigned int other = (unsigned int)__shfl_xor((int)us, 1);
            if (((l16 & 1) == 0) && row < N)
                C[(size_t)row * 64 + t * 8 + (l16 >> 1)] = us | (other << 16);
        }
    }
}

// ---------------- gather + self-loop + bias + leaky_relu (layer 2; R1-verified) -------------
__global__ __launch_bounds__(256) void combine_kernel(const uint4* __restrict__ h4,
                                                      const int* __restrict__ ptr,
                                                      const int2* __restrict__ csr_edge,
                                                      const float* __restrict__ dinv,
                                                      const float* __restrict__ b,
                                                      uint4* __restrict__ out4, int N) {
    __shared__ int2 smeta[4][64];
    int wave = threadIdx.x >> 6;
    int lane = threadIdx.x & 63;
    int q = lane >> 4;
    int l16 = lane & 15;
    int nb = blockIdx.x * 16 + wave * 4;
    if (nb >= N) return;  // wave-uniform exit; kernel uses no barriers
    int node = nb + q;
    bool valid = node < N;

    int wlo = ptr[nb];
    int whi = ptr[min(nb + 4, N)];
    int lo = valid ? ptr[node] : 0;
    int hi = valid ? ptr[node + 1] : 0;

    float di = valid ? dinv[node] : 0.f;
    uint4 sv = valid ? h4[(size_t)node * 16 + l16] : make_uint4(0u, 0u, 0u, 0u);
    float4 bv0 = ((const float4*)b)[l16 * 2];
    float4 bv1 = ((const float4*)b)[l16 * 2 + 1];

    float a0 = 0.f, a1 = 0.f, a2 = 0.f, a3 = 0.f, a4 = 0.f, a5 = 0.f, a6 = 0.f, a7 = 0.f;

#pragma unroll 1
    for (int base = wlo; base < whi; base += 64) {
        if (base + lane < whi) smeta[wave][lane] = csr_edge[base + lane];
        int s = max(lo, base);
        int e = min(hi, base + 64);
        int j = s;
#pragma unroll 1
        for (; j + 3 < e; j += 4) {
            int k = j - base;
            int2 e0 = smeta[wave][k];
            int2 e1 = smeta[wave][k + 1];
            int2 e2 = smeta[wave][k + 2];
            int2 e3 = smeta[wave][k + 3];
            uint4 v0 = h4[(size_t)e0.x * 16 + l16];
            uint4 v1 = h4[(size_t)e1.x * 16 + l16];
            uint4 v2 = h4[(size_t)e2.x * 16 + l16];
            uint4 v3 = h4[(size_t)e3.x * 16 + l16];
            float c0 = __int_as_float(e0.y);
            float c1 = __int_as_float(e1.y);
            float c2 = __int_as_float(e2.y);
            float c3 = __int_as_float(e3.y);
            ACC8(v0, c0)
            ACC8(v1, c1)
            ACC8(v2, c2)
            ACC8(v3, c3)
        }
#pragma unroll 1
        for (; j < e; j++) {
            int k = j - base;
            int2 e0 = smeta[wave][k];
            uint4 v0 = h4[(size_t)e0.x * 16 + l16];
            float c0 = __int_as_float(e0.y);
            ACC8(v0, c0)
        }
    }

    if (!valid) return;
    float dd = di * di;
    float v0 = a0 + bf2f(sv.x & 0xffffu) * dd + bv0.x;
    float v1 = a1 + bf2f(sv.x >> 16) * dd + bv0.y;
    float v2 = a2 + bf2f(sv.y & 0xffffu) * dd + bv0.z;
    float v3 = a3 + bf2f(sv.y >> 16) * dd + bv0.w;
    float v4 = a4 + bf2f(sv.z & 0xffffu) * dd + bv1.x;
    float v5 = a5 + bf2f(sv.z >> 16) * dd + bv1.y;
    float v6 = a6 + bf2f(sv.w & 0xffffu) * dd + bv1.z;
    float v7 = a7 + bf2f(sv.w >> 16) * dd + bv1.w;
    v0 = (v0 >= 0.f) ? v0 : NEG * v0;
    v1 = (v1 >= 0.f) ? v1 : NEG * v1;
    v2 = (v2 >= 0.f) ? v2 : NEG * v2;
    v3 = (v3 >= 0.f) ? v3 : NEG * v3;
    v4 = (v4 >= 0.f) ? v4 : NEG * v4;
    v5 = (v5 >= 0.f) ? v5 : NEG * v5;
    v6 = (v6 >= 0.f) ? v6 : NEG * v6;
    v7 = (v7 >= 0.f) ? v7 : NEG * v7;
    uint4 pv;
    pv.x = (unsigned int)f2bf(v0) | ((unsigned int)f2bf(v1) << 16);
    pv.y = (unsigned int)f2bf(v2) | ((unsigned int)f2bf(v3) << 16);
    pv.z = (unsigned int)f2bf(v4) | ((unsigned int)f2bf(v5) << 16);
    pv.w = (unsigned int)f2bf(v6) | ((unsigned int)f2bf(v7) << 16);
    out4[(size_t)node * 16 + l16] = pv;
}

// ---------------- pool: node-parallel chunked accumulate (batch sorted) ----------------
#define PROWS 128
__global__ void pool_accum_kernel(const unsigned int* __restrict__ a2,
                                  const int* __restrict__ batch,
                                  float* __restrict__ pooled, int N) {
    int wave = threadIdx.x >> 6;
    int lane = threadIdx.x & 63;
    int start = blockIdx.x * PROWS;
    int end = start + PROWS;
    if (end > N) end = N;
    float s0 = 0.f, s1 = 0.f;
    int curg = -1;
    for (int r = start + wave; r < end; r += 4) {
        int g = batch[r];
        if (g != curg) {
            if (curg >= 0) {
                atomicAdd(&pooled[curg * D + 2 * lane], s0);
                atomicAdd(&pooled[curg * D + 2 * lane + 1], s1);
            }
            curg = g;
            s0 = 0.f;
            s1 = 0.f;
        }
        unsigned int v = a2[(size_t)r * 64 + lane];
        s0 += bf2f(v & 0xffffu);
        s1 += bf2f(v >> 16);
    }
    if (curg >= 0) {
        atomicAdd(&pooled[curg * D + 2 * lane], s0);
        atomicAdd(&pooled[curg * D + 2 * lane + 1], s1);
    }
}

// ---------------- final linear ----------------
__global__ void final_kernel(const float* __restrict__ pooled, const int* __restrict__ batch,
                             const float* __restrict__ Wl, const float* __restrict__ bl,
                             float* __restrict__ out, int N) {
    int t = blockIdx.x * blockDim.x + threadIdx.x;
    if (t >= NG * NC) return;
    int g = t >> 4, c = t & 15;
    int l = 0, h = N;
    while (l < h) { int m = (l + h) >> 1; if (batch[m] < g) l = m + 1; else h = m; }
    int lo = l;
    h = N;
    while (l < h) { int m = (l + h) >> 1; if (batch[m] < g + 1) l = m + 1; else h = m; }
    int cnt = l - lo;
    float inv = 1.0f / (float)(cnt > 0 ? cnt : 1);
    float dot = 0.f;
    for (int k = 0; k < D; k++) dot += pooled[g * D + k] * Wl[k * NC + c];
    out[t] = dot * inv + bl[c];
}

extern "C" void kernel_launch(void* const* d_in, const int* in_sizes, int n_in,
                              void* d_out, int out_size, void* d_ws, size_t ws_size,
                              hipStream_t stream) {
    const float* x = (const float*)d_in[0];
    const int* ei = (const int*)d_in[1];
    const int* batch = (const int*)d_in[2];
    const float* W1 = (const float*)d_in[3];
    const float* b1 = (const float*)d_in[4];
    const float* W2 = (const float*)d_in[5];
    const float* b2 = (const float*)d_in[6];
    const float* Wlin = (const float*)d_in[7];
    const float* bl = (const float*)d_in[8];
    float* out = (float*)d_out;

    int N = in_sizes[0] / D;
    int E = in_sizes[1] / 2;
    const int* src = ei;
    const int* dst = ei + E;

    float* ws = (float*)d_ws;
    size_t o = 0;
    unsigned int* bufA = (unsigned int*)(ws + o); o += (size_t)N * 64;  // 12.8 MB
    unsigned int* bufB = (unsigned int*)(ws + o); o += (size_t)N * 64;  // 12.8 MB
    int* deg = (int*)(ws + o);      o += N;
    int* fill = (int*)(ws + o);     o += N;
    float* dinv = ws + o;           o += N;
    int* scan1 = (int*)(ws + o);    o += N;
    int* blocksum = (int*)(ws + o); o += 256;
    int* csr_ptr = (int*)(ws + o);  o += (N + 4);
    int2* csr_edge = (int2*)(ws + o); o += (size_t)2 * E;
    float* pooled = ws + o;         o += NG * D;
    unsigned short* Wf2 = (unsigned short*)(ws + o); o += 8192;

    hipMemsetAsync(deg, 0, (size_t)N * sizeof(int), stream);

    int tb = 256;
    int nscan = (N + 255) / 256;
    int gblocks = (N + 63) / 64;
    int cblocks = (N + 15) / 16;
    int eblocks = (E + 255) / 256;

    // fused: layer-1 GEMM || {Wf2 image, pooled zero, degree histogram}
    prep_gemm1_kernel<<<gblocks + 40 + eblocks, 256, 0, stream>>>(
        x, W1, (unsigned int*)bufA, gblocks, W2, Wf2, pooled, dst, deg, E, N);
    scan_block_kernel<<<nscan, 256, 0, stream>>>(deg, scan1, blocksum, dinv, N);
    finalize_ptr_kernel<<<nscan, 256, 0, stream>>>(deg, scan1, blocksum, csr_ptr, fill,
                                                   nscan, N, E);
    scatter_kernel<<<(E + tb - 1) / tb, tb, 0, stream>>>(src, dst, fill, dinv,
                                                         csr_edge, E);

    // fused combine(layer1)+gemm2: bufA(G1) -> bufB(h1@W2). No h1 round-trip, no gemm2 launch.
    combine_gemm_kernel<<<cblocks, 256, 0, stream>>>((const uint4*)bufA, csr_ptr, csr_edge,
                                                     dinv, b1, (const uint4*)Wf2,
                                                     (unsigned int*)bufB, N);
    // layer-2 combine: bufB -> bufA
    combine_kernel<<<cblocks, 256, 0, stream>>>((const uint4*)bufB, csr_ptr, csr_edge,
                                                dinv, b2, (uint4*)bufA, N);
    // pool + classifier
    pool_accum_kernel<<<(N + PROWS - 1) / PROWS, 256, 0, stream>>>(bufA, batch, pooled, N);
    final_kernel<<<(NG * NC + tb - 1) / tb, tb, 0, stream>>>(pooled, batch, Wlin, bl, out, N);
}